// Round 1
// baseline (409.095 us; speedup 1.0000x reference)
//
#include <hip/hip_runtime.h>

namespace {

constexpr int H = 17, W = 17, NC = H * W;   // 289 cells
constexpr int SW_ = 20, SH_ = 19;           // LDS tile (1-wide zero halo), row stride 20
constexpr int NT = 320;                     // 5 waves, one workgroup

__device__ __forceinline__ float clip10(float v) {
    return fminf(fmaxf(v, -10.f), 10.f);
}

__launch_bounds__(NT, 1)
__global__ void ca_kernel(const float* __restrict__ cell_in,
                          const float* __restrict__ food,
                          const float* __restrict__ w3,
                          const float* __restrict__ b3,
                          const float* __restrict__ w4,
                          const float* __restrict__ b4,
                          const int* __restrict__ steps_p,
                          float* __restrict__ out)
{
    __shared__ float c0[SH_ * SW_];
    __shared__ float c1[SH_ * SW_];
    __shared__ float c2[SH_ * SW_];
    __shared__ float c3[SH_ * SW_];
    __shared__ float xb[SH_ * SW_];   // x[0] exchange buffer for post-alive maxpool
    __shared__ float red[NT];

    const int tid = (int)threadIdx.x;
    const int steps = steps_p[0];
    const bool active = tid < NC;

    // zero all LDS tiles (halos must be 0 for SAME-pad convs / maxpool decision)
    for (int i = tid; i < SH_ * SW_; i += NT) {
        c0[i] = 0.f; c1[i] = 0.f; c2[i] = 0.f; c3[i] = 0.f; xb[i] = 0.f;
    }
    __syncthreads();

    const int hy = active ? tid / W : 0;
    const int wx = active ? tid % W : 0;
    const int idx = (hy + 1) * SW_ + (wx + 1);

    if (active) {
        c0[idx] = cell_in[tid];
        c1[idx] = cell_in[NC + tid];
        c2[idx] = cell_in[2 * NC + tid];
        // channel 3 of the input is never used: it is overwritten with scent
        // at the top of every update before any read.

        // scent = 5x5 cross-correlation of SCENT_K over food (zero pad), loop-invariant
        const float SK[5][5] = {
            {0.f,   .125f, .25f, .125f, 0.f},
            {.125f, .25f,  .5f,  .25f,  .125f},
            {.25f,  .5f,   1.f,  .5f,   .25f},
            {.125f, .25f,  .5f,  .25f,  .125f},
            {0.f,   .125f, .25f, .125f, 0.f}};
        float sc = 0.f;
        #pragma unroll
        for (int dy = -2; dy <= 2; ++dy) {
            #pragma unroll
            for (int dxo = -2; dxo <= 2; ++dxo) {
                const float k = SK[dy + 2][dxo + 2];
                if (k != 0.f) {
                    const int yy = hy + dy, xx = wx + dxo;
                    if (yy >= 0 && yy < H && xx >= 0 && xx < W)
                        sc = fmaf(k, food[yy * W + xx], sc);
                }
            }
        }
        c3[idx] = sc;
    }
    __syncthreads();

    // loop-invariant scent-channel perception (dx/dy of scent, scent center)
    float s_ctr = 0.f, dx3s = 0.f, dy3s = 0.f;
    if (active) {
        const float a00 = c3[idx - SW_ - 1], a01 = c3[idx - SW_], a02 = c3[idx - SW_ + 1];
        const float a10 = c3[idx - 1],       a11 = c3[idx],       a12 = c3[idx + 1];
        const float a20 = c3[idx + SW_ - 1], a21 = c3[idx + SW_], a22 = c3[idx + SW_ + 1];
        s_ctr = a11;
        dx3s = ((a02 - a00) + 2.f * (a12 - a10) + (a22 - a20)) * 0.125f;
        dy3s = ((a20 + 2.f * a21 + a22) - (a00 + 2.f * a01 + a02)) * 0.125f;
    }

    for (int s = 0; s < steps; ++s) {
        float nx0 = 0.f, nx1 = 0.f, nx2 = 0.f;
        bool pre = false;
        if (active) {
            // ---- channel 0 (also pre-alive maxpool) ----
            float a00 = c0[idx - SW_ - 1], a01 = c0[idx - SW_], a02 = c0[idx - SW_ + 1];
            float a10 = c0[idx - 1],       a11 = c0[idx],       a12 = c0[idx + 1];
            float a20 = c0[idx + SW_ - 1], a21 = c0[idx + SW_], a22 = c0[idx + SW_ + 1];
            const float ctr0 = a11;
            const float dx0 = ((a02 - a00) + 2.f * (a12 - a10) + (a22 - a20)) * 0.125f;
            const float dy0 = ((a20 + 2.f * a21 + a22) - (a00 + 2.f * a01 + a02)) * 0.125f;
            float mx = fmaxf(fmaxf(fmaxf(a00, a01), fmaxf(a02, a10)),
                             fmaxf(fmaxf(a11, a12), fmaxf(fmaxf(a20, a21), a22)));
            pre = mx > 0.1f;
            // ---- channel 1 ----
            a00 = c1[idx - SW_ - 1]; a01 = c1[idx - SW_]; a02 = c1[idx - SW_ + 1];
            a10 = c1[idx - 1];       a11 = c1[idx];       a12 = c1[idx + 1];
            a20 = c1[idx + SW_ - 1]; a21 = c1[idx + SW_]; a22 = c1[idx + SW_ + 1];
            const float ctr1 = a11;
            const float dx1 = ((a02 - a00) + 2.f * (a12 - a10) + (a22 - a20)) * 0.125f;
            const float dy1 = ((a20 + 2.f * a21 + a22) - (a00 + 2.f * a01 + a02)) * 0.125f;
            // ---- channel 2 ----
            a00 = c2[idx - SW_ - 1]; a01 = c2[idx - SW_]; a02 = c2[idx - SW_ + 1];
            a10 = c2[idx - 1];       a11 = c2[idx];       a12 = c2[idx + 1];
            a20 = c2[idx + SW_ - 1]; a21 = c2[idx + SW_]; a22 = c2[idx + SW_ + 1];
            const float ctr2 = a11;
            const float dx2 = ((a02 - a00) + 2.f * (a12 - a10) + (a22 - a20)) * 0.125f;
            const float dy2 = ((a20 + 2.f * a21 + a22) - (a00 + 2.f * a01 + a02)) * 0.125f;

            // ---- MLP: h = relu(w3 @ y + b3); delta(rows 0..2) = w4 @ h + b4 ----
            const float yv[12] = {ctr0, ctr1, ctr2, s_ctr,
                                  dx0,  dx1,  dx2,  dx3s,
                                  dy0,  dy1,  dy2,  dy3s};
            float d0 = b4[0], d1 = b4[1], d2 = b4[2];
            #pragma unroll
            for (int o = 0; o < 16; ++o) {
                float a = b3[o];
                #pragma unroll
                for (int c = 0; c < 12; ++c)
                    a = fmaf(w3[o * 12 + c], yv[c], a);
                a = fmaxf(a, 0.f);           // relu
                d0 = fmaf(w4[o],      a, d0);
                d1 = fmaf(w4[16 + o], a, d1);
                d2 = fmaf(w4[32 + o], a, d2);
            }
            nx0 = ctr0 + d0;
            nx1 = ctr1 + d1;
            nx2 = ctr2 + d2;
            xb[idx] = nx0;                    // publish x[0] for post-alive maxpool
        }
        __syncthreads();
        if (active) {
            const float p00 = xb[idx - SW_ - 1], p01 = xb[idx - SW_], p02 = xb[idx - SW_ + 1];
            const float p10 = xb[idx - 1],       p11 = xb[idx],       p12 = xb[idx + 1];
            const float p20 = xb[idx + SW_ - 1], p21 = xb[idx + SW_], p22 = xb[idx + SW_ + 1];
            const float mx2 = fmaxf(fmaxf(fmaxf(p00, p01), fmaxf(p02, p10)),
                                    fmaxf(fmaxf(p11, p12), fmaxf(fmaxf(p20, p21), p22)));
            const bool post = mx2 > 0.1f;
            const float m = (pre && post) ? 1.f : 0.f;
            c0[idx] = clip10(nx0 * m);
            c1[idx] = clip10(nx1 * m);
            c2[idx] = clip10(nx2 * m);
            // channel 3 stays = scent (restored each step in the reference)
        }
        __syncthreads();
    }

    // ---- outputs: cell (4*289), food (289), living_count (1) ----
    float v0 = 0.f;
    if (active) {
        v0 = c0[idx];
        out[tid]            = v0;
        out[NC + tid]       = c1[idx];
        out[2 * NC + tid]   = c2[idx];
        out[3 * NC + tid]   = clip10(c3[idx]);
        out[4 * NC + tid]   = food[tid];
        red[tid] = v0;
    } else {
        red[tid] = 0.f;
    }
    __syncthreads();
    if (tid < 17) {
        float sum = 0.f;
        for (int i = 0; i < 17; ++i) sum += red[tid * 17 + i];
        red[NC + tid] = sum;    // disjoint slots (289..305), no race with reads
    }
    __syncthreads();
    if (tid == 0) {
        float sum = 0.f;
        for (int i = 0; i < 17; ++i) sum += red[NC + i];
        out[5 * NC] = sum;      // element 1445
    }
}

}  // namespace

extern "C" void kernel_launch(void* const* d_in, const int* in_sizes, int n_in,
                              void* d_out, int out_size, void* d_ws, size_t ws_size,
                              hipStream_t stream) {
    const float* cell = (const float*)d_in[0];
    const float* food = (const float*)d_in[1];
    const float* w3   = (const float*)d_in[2];
    const float* b3   = (const float*)d_in[3];
    const float* w4   = (const float*)d_in[4];
    const float* b4   = (const float*)d_in[5];
    const int*   st   = (const int*)d_in[6];
    float* out = (float*)d_out;
    ca_kernel<<<1, NT, 0, stream>>>(cell, food, w3, b3, w4, b4, st, out);
}